// Round 7
// baseline (336.036 us; speedup 1.0000x reference)
//
#include <hip/hip_runtime.h>

// TransformerLayer on MI355X (gfx950), bf16 MFMA pipeline, fp32 LN/softmax/accum.
// R7: FFN2 split-K=3 (768 blocks = 3/CU; partials into dead W1t/x/xb region),
// W1/W2 transposes fused into the QKV GEMM launch (overlap BW work with the
// latency-bound GEMM), LN1 + QKV-weight transpose fused into one prologue.
// GEMM core + attention = R6 (verified: 0 bank conflicts, absmax 0.031).

typedef unsigned short u16;
typedef unsigned int   u32;
typedef __bf16 bf16x8 __attribute__((ext_vector_type(8)));
typedef float  f32x4  __attribute__((ext_vector_type(4)));

#define NEG_INF (-__builtin_inff())

#if __has_builtin(__builtin_amdgcn_exp2f)
#define EXP2F(x) __builtin_amdgcn_exp2f(x)
#else
#define EXP2F(x) exp2f(x)
#endif

__device__ __forceinline__ u32 pack_bf16_trunc(float a, float b) {
#if __has_builtin(__builtin_amdgcn_perm)
  return __builtin_amdgcn_perm(__float_as_uint(b), __float_as_uint(a), 0x07060302u);
#else
  return (__float_as_uint(a) >> 16) | (__float_as_uint(b) & 0xFFFF0000u);
#endif
}

// fp32 -> bf16 RNE (finite inputs only)
__device__ __forceinline__ u16 f2b(float f) {
  u32 u = __float_as_uint(f);
  u = (u + 0x7fffu + ((u >> 16) & 1u)) >> 16;
  return (u16)u;
}

// async global->LDS, 16B per lane. LDS dest must be wave-uniform base + lane*16.
__device__ __forceinline__ void gload16(const void* g, void* l) {
  __builtin_amdgcn_global_load_lds(
      (const __attribute__((address_space(1))) u32*)g,
      (__attribute__((address_space(3))) u32*)l, 16, 0, 0);
}

__device__ __forceinline__ bf16x8 ld16(const u16* p) { return *(const bf16x8*)p; }

// ---------------------------------------------------------------------------
// LayerNorm body (row of 1024). 256 threads.
__device__ __forceinline__
void ln_body(int row, const float* __restrict__ in, const float* __restrict__ in2,
             const float* __restrict__ w, const float* __restrict__ b,
             float* __restrict__ outf, u16* __restrict__ outb) {
  int t = threadIdx.x;
  const float4* ip = (const float4*)(in + (size_t)row * 1024);
  float4 x = ip[t];
  if (in2) {
    const float4* ip2 = (const float4*)(in2 + (size_t)row * 1024);
    float4 o = ip2[t];
    x.x += o.x; x.y += o.y; x.z += o.z; x.w += o.w;
  }
  float s = x.x + x.y + x.z + x.w;
  float q = x.x * x.x + x.y * x.y + x.z * x.z + x.w * x.w;
#pragma unroll
  for (int m = 32; m; m >>= 1) { s += __shfl_xor(s, m); q += __shfl_xor(q, m); }
  __shared__ float rs[4], rq[4];
  if ((t & 63) == 0) { rs[t >> 6] = s; rq[t >> 6] = q; }
  __syncthreads();
  s = rs[0] + rs[1] + rs[2] + rs[3];
  q = rq[0] + rq[1] + rq[2] + rq[3];
  float mean = s * (1.f / 1024.f);
  float var  = q * (1.f / 1024.f) - mean * mean;
  float rstd = rsqrtf(var + 1e-5f);
  float4 wv = ((const float4*)w)[t];
  float4 bv = ((const float4*)b)[t];
  float4 y;
  y.x = (x.x - mean) * rstd * wv.x + bv.x;
  y.y = (x.y - mean) * rstd * wv.y + bv.y;
  y.z = (x.z - mean) * rstd * wv.z + bv.z;
  y.w = (x.w - mean) * rstd * wv.w + bv.w;
  if (outf) ((float4*)(outf + (size_t)row * 1024))[t] = y;
  ushort4 ub;
  ub.x = f2b(y.x); ub.y = f2b(y.y); ub.z = f2b(y.z); ub.w = f2b(y.w);
  ((ushort4*)(outb + (size_t)row * 1024))[t] = ub;
}

// 64x64 fp32->bf16 transpose tile body through LDS (tile = 64*65 floats).
__device__ __forceinline__
void trans_body(float* tile, const float* __restrict__ in, u16* __restrict__ out,
                int R, int C, int r0, int c0) {
  int tr = threadIdx.x >> 6, tc = threadIdx.x & 63;
#pragma unroll
  for (int i = 0; i < 16; i++) {
    int r = i * 4 + tr;
    tile[r * 65 + tc] = in[(size_t)(r0 + r) * C + c0 + tc];
  }
  __syncthreads();
#pragma unroll
  for (int i = 0; i < 16; i++) {
    int c = i * 4 + tr;
    out[(size_t)(c0 + c) * R + r0 + tc] = f2b(tile[tc * 65 + c]);
  }
}

// ---------------------------------------------------------------------------
// Prologue: LN1 (blocks 0..4095) + QKV weight transpose (blocks 4096..4863).
__global__ __launch_bounds__(256)
void prologue_k(const float* __restrict__ emb, const float* __restrict__ ln1w,
                const float* __restrict__ ln1b, float* __restrict__ x,
                u16* __restrict__ xb, const float* __restrict__ Wq,
                const float* __restrict__ Wk, const float* __restrict__ Wv,
                u16* __restrict__ Wqkv_t) {
  __shared__ float tile[64 * 65];
  int bx = blockIdx.x;
  if (bx < 4096) {
    ln_body(bx, emb, nullptr, ln1w, ln1b, x, xb);
  } else {
    int id = bx - 4096;                 // 0..767
    int z = id >> 4, sub = z & 15, which = z >> 4;
    const float* in = which == 0 ? Wq : (which == 1 ? Wk : Wv);
    // per 1024x64 head-matrix: transpose to [64][1024] at Wqkv_t + which*1M + sub*64*1024
    trans_body(tile, in + (size_t)sub * 1024 * 64,
               Wqkv_t + (size_t)which * 1024 * 1024 + (size_t)sub * 64 * 1024,
               1024, 64, (id & 15) * 64, 0);
  }
}

// ---------------------------------------------------------------------------
// bf16 transpose for V: vin [bh][2048][64] -> vt [bh][64][2048]
__global__ __launch_bounds__(256)
void vtrans_k(const u16* __restrict__ vin, u16* __restrict__ vt) {
  __shared__ __align__(16) u16 tile[64][72];
  int s0 = blockIdx.x * 64, bh = blockIdx.y;
  const u16* ip = vin + (size_t)bh * 2048 * 64;
  u16* op = vt + (size_t)bh * 64 * 2048;
  int t = threadIdx.x;
#pragma unroll
  for (int i = 0; i < 2; i++) {
    int idx = i * 256 + t, r = idx >> 3, c = idx & 7;
    *(uint4*)&tile[r][c * 8] = *(const uint4*)(ip + (size_t)(s0 + r) * 64 + c * 8);
  }
  __syncthreads();
#pragma unroll
  for (int i = 0; i < 16; i++) {
    int d = i * 4 + (t >> 6), s = t & 63;
    op[(size_t)d * 2048 + s0 + s] = tile[s][d];
  }
}

// ---------------------------------------------------------------------------
// LayerNorm standalone (for LN2).
__global__ __launch_bounds__(256)
void ln_k(const float* __restrict__ in, const float* __restrict__ in2,
          const float* __restrict__ w, const float* __restrict__ b,
          float* __restrict__ outf, u16* __restrict__ outb) {
  ln_body(blockIdx.x, in, in2, w, b, outf, outb);
}

// ---------------------------------------------------------------------------
// 128x128 tile bf16 GEMM body, BK=64, 256 threads (4 waves, 2x2 of 64x64).
// XOR chunk swizzle -> conflict-free ds_read_b128 (verified: 0 conflicts).
#define EPI_QKV  0
#define EPI_RELU 1
#define EPI_RES  2

// 0.125 * log2(e): folds the 1/sqrt(64) score scale AND the exp->exp2
// conversion into the Q projection (attention uses exp2 directly).
#define QSCALE 0.18033688011112042f

template <int EPI>
__device__ __forceinline__
void gemm_body(u16* __restrict__ As, u16* __restrict__ Bs,
               const u16* __restrict__ A, const u16* __restrict__ Bt,
               int bxm, int bxn, int kbeg, int klen, int lda, int ldbt,
               const float* __restrict__ bias0, const float* __restrict__ bias1,
               const float* __restrict__ bias2, const float* __restrict__ res,
               int ldout, u16* __restrict__ outb, float* __restrict__ outf,
               float* __restrict__ p1, float* __restrict__ p2, int z) {
  int t = threadIdx.x;
  int wave = t >> 6, lane = t & 63, quad = lane >> 4, l16 = lane & 15;
  int x7 = l16 & 7;
  int wm = (wave >> 1) * 64, wn = (wave & 1) * 64;
  int bm = bxm * 128, bn = bxn * 128;

  const u16* Agl[4];
  const u16* Bgl[4];
#pragma unroll
  for (int i = 0; i < 4; i++) {
    int idx = i * 256 + t, r = idx >> 3, c = (idx & 7) ^ (r & 7);
    Agl[i] = A + (size_t)(bm + r) * lda + kbeg + c * 8;
    Bgl[i] = Bt + (size_t)(bn + r) * ldbt + kbeg + c * 8;
  }
  u16* Asl = As + t * 8;
  u16* Bsl = Bs + t * 8;

  f32x4 acc[4][4] = {};

  for (int k0 = 0; k0 < klen; k0 += 64) {
#pragma unroll
    for (int i = 0; i < 4; i++) {
      gload16(Agl[i] + k0, Asl + i * 2048);
      gload16(Bgl[i] + k0, Bsl + i * 2048);
    }
    __syncthreads();
#pragma unroll
    for (int kc = 0; kc < 2; kc++) {
      bf16x8 af[4], bfr[4];
#pragma unroll
      for (int i = 0; i < 4; i++) {
        int r = wm + i * 16 + l16;
        af[i] = *(const bf16x8*)(As + r * 64 + (((kc * 4 + quad) ^ x7) * 8));
      }
#pragma unroll
      for (int j = 0; j < 4; j++) {
        int r = wn + j * 16 + l16;
        bfr[j] = *(const bf16x8*)(Bs + r * 64 + (((kc * 4 + quad) ^ x7) * 8));
      }
#pragma unroll
      for (int i = 0; i < 4; i++)
#pragma unroll
        for (int j = 0; j < 4; j++)
          acc[i][j] = __builtin_amdgcn_mfma_f32_16x16x32_bf16(af[i], bfr[j],
                                                              acc[i][j], 0, 0, 0);
    }
    __syncthreads();
  }

#pragma unroll
  for (int i = 0; i < 4; i++) {
#pragma unroll
    for (int j = 0; j < 4; j++) {
      int c = bn + wn + j * 16 + l16;
#pragma unroll
      for (int rr = 0; rr < 4; rr++) {
        int r = bm + wm + i * 16 + quad * 4 + rr;
        float v = acc[i][j][rr];
        if (EPI == EPI_QKV) {
          int which = c >> 10, h = (c >> 6) & 15, d = c & 63;
          const float* bp = which == 0 ? bias0 : (which == 1 ? bias1 : bias2);
          v += bp[h * 64 + d];
          if (which == 0) v *= QSCALE;  // prescale Q for base-2 softmax
          int bb = r >> 11, ss = r & 2047;
          outb[((size_t)(which * 32 + bb * 16 + h) * 2048 + ss) * 64 + d] = f2b(v);
        } else if (EPI == EPI_RELU) {
          v += bias0[c];
          v = v > 0.f ? v : 0.f;
          outb[(size_t)r * ldout + c] = f2b(v);
        } else {
          if (z == 0) {
            v += bias0[c] + res[(size_t)r * ldout + c];
            outf[(size_t)r * ldout + c] = v;
          } else if (z == 1) {
            p1[(size_t)r * ldout + c] = v;
          } else {
            p2[(size_t)r * ldout + c] = v;
          }
        }
      }
    }
  }
}

// QKV GEMM (blocks 0..767, flattened 32x24) + W1/W2 transpose (blocks 768..2815)
// fused into one launch: transposes are pure-BW work that fills the GEMM's
// latency bubbles; they touch none of the GEMM's inputs/outputs.
__global__ __launch_bounds__(256)
void qkv_plus_k(const u16* __restrict__ xb, const u16* __restrict__ Wqkv_t,
                const float* __restrict__ bq, const float* __restrict__ bk,
                const float* __restrict__ bv, u16* __restrict__ qkvb,
                const float* __restrict__ W1, const float* __restrict__ W2,
                u16* __restrict__ W1t, u16* __restrict__ W2t) {
  __shared__ __align__(16) u16 SM[2][128 * 64];
  int bx = blockIdx.x;
  if (bx < 768) {
    gemm_body<EPI_QKV>(SM[0], SM[1], xb, Wqkv_t, bx & 31, bx >> 5, 0, 1024,
                       1024, 1024, bq, bk, bv, nullptr, 0, qkvb, nullptr,
                       nullptr, nullptr, 0);
  } else {
    int id = bx - 768;
    float* tile = (float*)SM;  // 64*65 floats = 16.6 KB, fits in SM
    if (id < 1024)
      trans_body(tile, W1, W1t, 1024, 4096, (id & 15) * 64, (id >> 4) * 64);
    else {
      id -= 1024;
      trans_body(tile, W2, W2t, 4096, 1024, (id >> 4) * 64, (id & 15) * 64);
    }
  }
}

__global__ __launch_bounds__(256)
void ffn1_gemm(const u16* __restrict__ A, const u16* __restrict__ Bt,
               const float* __restrict__ b0, u16* __restrict__ outb) {
  __shared__ __align__(16) u16 SM[2][128 * 64];
  gemm_body<EPI_RELU>(SM[0], SM[1], A, Bt, blockIdx.x, blockIdx.y, 0, 1024,
                      1024, 1024, b0, nullptr, nullptr, nullptr, 4096, outb,
                      nullptr, nullptr, nullptr, 0);
}

// FFN2 split-K=3: z0 K=[0,1408), z1 [1408,2752), z2 [2752,4096).
__global__ __launch_bounds__(256)
void ffn2_gemm(const u16* __restrict__ A, const u16* __restrict__ Bt,
               const float* __restrict__ b0, const float* __restrict__ res,
               float* __restrict__ outf, float* __restrict__ p1,
               float* __restrict__ p2) {
  __shared__ __align__(16) u16 SM[2][128 * 64];
  int z = blockIdx.z;
  int kbeg = z * 1344 + (z > 0 ? 64 : 0);
  int klen = 1344 + (z == 0 ? 64 : 0);
  gemm_body<EPI_RES>(SM[0], SM[1], A, Bt, blockIdx.x, blockIdx.y, kbeg, klen,
                     4096, 4096, b0, nullptr, nullptr, res, 1024, nullptr,
                     outf, p1, p2, z);
}

// out[i] += p1[i] + p2[i]  (fp32, float4)
__global__ __launch_bounds__(256)
void reduce2_k(float* __restrict__ out, const float* __restrict__ p1,
               const float* __restrict__ p2) {
  int i = blockIdx.x * 256 + threadIdx.x;
  float4 a = ((const float4*)p1)[i];
  float4 c = ((const float4*)p2)[i];
  float4 b = ((float4*)out)[i];
  b.x += a.x + c.x; b.y += a.y + c.y; b.z += a.z + c.z; b.w += a.w + c.w;
  ((float4*)out)[i] = b;
}

// ---------------------------------------------------------------------------
// Flash attention, causal. Grid (16, 32), 512 threads (8 waves). (= R6, verified)
__global__ __launch_bounds__(512, 6)
void attn_k(const u16* __restrict__ qkv, const u16* __restrict__ vt,
            float* __restrict__ o) {
  int bh = blockIdx.y, b = bh >> 4, h = bh & 15;
  int Qt = b ? (15 - (int)blockIdx.x) : (int)blockIdx.x;  // causal balance
  int t = threadIdx.x;
  int wave = t >> 6, lane = t & 63, quad = lane >> 4, l16 = lane & 15;
  int x7 = l16 & 7;
  int q0 = Qt * 128 + wave * 16;

  const u16* qg = qkv + (size_t)bh * (2048 * 64);
  const u16* kg = qkv + (size_t)(32 + bh) * (2048 * 64);
  const u16* vg = vt + (size_t)bh * (64 * 2048);  // [dh][s]

  __shared__ __align__(16) u16 Ks[2][64 * 64];
  __shared__ __align__(16) u16 Vs[2][64 * 64];
  __shared__ __align__(16) u16 Ps[8][16 * 64 + 32];  // +64B aux per wave
  u16* Pw = Ps[wave];
  float* auxf = (float*)(Pw + 1024);

  int sr = t >> 3, sc_ = (t & 7) ^ (sr & 7);

  gload16(kg + (size_t)sr * 64 + sc_ * 8, Ks[0] + t * 8);
  gload16(vg + (size_t)sr * 2048 + sc_ * 8, Vs[0] + t * 8);

  bf16x8 qf0 = ld16(qg + (size_t)(q0 + l16) * 64 + quad * 8);
  bf16x8 qf1 = ld16(qg + (size_t)(q0 + l16) * 64 + 32 + quad * 8);

  f32x4 oacc[4] = {};
  float mo = NEG_INF, ll = 0.f;
  int kmax_w = q0 >> 6;
  int klast = 2 * Qt + 1;

  __syncthreads();

  for (int kt = 0; kt <= klast; kt++) {
    const u16* ks = Ks[kt & 1];
    const u16* vs = Vs[kt & 1];
    if (kt < klast) {
      gload16(kg + (size_t)((kt + 1) * 64 + sr) * 64 + sc_ * 8, Ks[(kt + 1) & 1] + t * 8);
      gload16(vg + (size_t)sr * 2048 + (kt + 1) * 64 + sc_ * 8, Vs[(kt + 1) & 1] + t * 8);
    }
    if (kt <= kmax_w) {
      // ---- S^T: A = K rows (m = kv), B = Q rows (n = q) ----
      f32x4 sc[4];
#pragma unroll
      for (int g = 0; g < 4; g++) {
        const u16* kr = ks + (g * 16 + l16) * 64;
        bf16x8 kf0 = *(const bf16x8*)(kr + ((quad ^ x7) * 8));
        bf16x8 kf1 = *(const bf16x8*)(kr + (((4 + quad) ^ x7) * 8));
        f32x4 s = {};
        s = __builtin_amdgcn_mfma_f32_16x16x32_bf16(kf0, qf0, s, 0, 0, 0);
        s = __builtin_amdgcn_mfma_f32_16x16x32_bf16(kf1, qf1, s, 0, 0, 0);
        sc[g] = s;
      }

      if (kt == kmax_w) {  // diagonal tile: mask kv > q
#pragma unroll
        for (int g = 0; g < 4; g++) {
          int kvb = kt * 64 + g * 16 + quad * 4;
#pragma unroll
          for (int rr = 0; rr < 4; rr++)
            if (kvb + rr > q0 + l16) sc[g][rr] = NEG_INF;
        }
      }

      // ---- online softmax, row = q = l16 ----
      float mx = sc[0][0];
#pragma unroll
      for (int g = 0; g < 4; g++)
#pragma unroll
        for (int rr = 0; rr < 4; rr++) mx = fmaxf(mx, sc[g][rr]);
      mx = fmaxf(mx, __shfl_xor(mx, 16));
      mx = fmaxf(mx, __shfl_xor(mx, 32));
      float mnew = fmaxf(mo, mx);
      float al = EXP2F(mo - mnew);
      mo = mnew;

      float sum = 0.f;
#pragma unroll
      for (int g = 0; g < 4; g++) {
        float p0 = EXP2F(sc[g][0] - mnew);
        float p1 = EXP2F(sc[g][1] - mnew);
        float p2 = EXP2F(sc[g][2] - mnew);
        float p3 = EXP2F(sc[g][3] - mnew);
        sum += (p0 + p1) + (p2 + p3);
        u32 lo = pack_bf16_trunc(p0, p1);
        u32 hi = pack_bf16_trunc(p2, p3);
        int slot = (2 * g + (quad >> 1)) ^ x7;
        *(uint2*)(Pw + l16 * 64 + slot * 8 + (quad & 1) * 4) = make_uint2(lo, hi);
      }
      sum += __shfl_xor(sum, 16);
      sum += __shfl_xor(sum, 32);
      ll = ll * al + sum;

      // rescale O: alpha indexed by q=l16 -> broadcast via per-wave LDS aux
      if (lane < 16) auxf[lane] = al;
      f32x4 av = *(const f32x4*)(auxf + quad * 4);
#pragma unroll
      for (int g = 0; g < 4; g++)
#pragma unroll
        for (int rr = 0; rr < 4; rr++) oacc[g][rr] *= av[rr];

      // ---- O += P(A) x V^T(B) ----
      bf16x8 pf0 = *(const bf16x8*)(Pw + l16 * 64 + ((quad ^ x7) * 8));
      bf16x8 pf1 = *(const bf16x8*)(Pw + l16 * 64 + (((4 + quad) ^ x7) * 8));
#pragma unroll
      for (int g = 0; g < 4; g++) {
        const u16* vr = vs + (g * 16 + l16) * 64;
        bf16x8 vf0 = *(const bf16x8*)(vr + ((quad ^ x7) * 8));
        bf16x8 vf1 = *(const bf16x8*)(vr + (((4 + quad) ^ x7) * 8));
        oacc[g] = __builtin_amdgcn_mfma_f32_16x16x32_bf16(pf0, vf0, oacc[g], 0, 0, 0);
        oacc[g] = __builtin_amdgcn_mfma_f32_16x16x32_bf16(pf1, vf1, oacc[g], 0, 0, 0);
      }
    }
    __syncthreads();
  }

  // epilogue: O row = m = quad*4+rr, col = dh = g*16+l16; l indexed by l16
  if (lane < 16) auxf[lane] = ll;
  f32x4 lv = *(const f32x4*)(auxf + quad * 4);
  float rinv[4];
#pragma unroll
  for (int rr = 0; rr < 4; rr++) rinv[rr] = 1.f / lv[rr];
  float* op = o + ((size_t)b * 2048 + q0) * 1024 + h * 64;
#pragma unroll
  for (int g = 0; g < 4; g++)
#pragma unroll
    for (int rr = 0; rr < 4; rr++)
      op[(size_t)(quad * 4 + rr) * 1024 + g * 16 + l16] = oacc[g][rr] * rinv[rr];
}

// ---------------------------------------------------------------------------
extern "C" void kernel_launch(void* const* d_in, const int* in_sizes, int n_in,
                              void* d_out, int out_size, void* d_ws, size_t ws_size,
                              hipStream_t stream) {
  const float* emb  = (const float*)d_in[0];
  const float* Wq   = (const float*)d_in[1];
  const float* bq   = (const float*)d_in[2];
  const float* Wk   = (const float*)d_in[3];
  const float* bk   = (const float*)d_in[4];
  const float* Wv   = (const float*)d_in[5];
  const float* bv   = (const float*)d_in[6];
  const float* ln1w = (const float*)d_in[7];
  const float* ln1b = (const float*)d_in[8];
  const float* ln2w = (const float*)d_in[9];
  const float* ln2b = (const float*)d_in[10];
  const float* W1   = (const float*)d_in[11];
  const float* b1   = (const float*)d_in[12];
  const float* W2   = (const float*)d_in[13];
  const float* b2   = (const float*)d_in[14];
  float* out = (float*)d_out;

  // Layout chosen so [W1t, x, xb] is one contiguous 33.6 MB region that is
  // fully dead at FFN2 time (W1t after FFN1, x after LN2, xb after QKV):
  // holds the two split-K partials p1/p2.
  char* p = (char*)d_ws;
  u16*   Wqkv_t = (u16*)p;   p += (size_t)3072 * 1024 * 2;   // 6 MB
  u16*   W2t    = (u16*)p;   p += (size_t)1024 * 4096 * 2;   // 8.4 MB
  u16*   W1t    = (u16*)p;   p += (size_t)4096 * 1024 * 2;   // 8.4 MB
  float* x      = (float*)p; p += (size_t)4096 * 1024 * 4;   // 16.8 MB
  u16*   xb     = (u16*)p;   p += (size_t)4096 * 1024 * 2;   // 8.4 MB
  u16*   qkvb   = (u16*)p;   p += (size_t)3 * 32 * 2048 * 64 * 2;  // 25.2 MB
  float* ob     = (float*)p; p += (size_t)4096 * 1024 * 4;   // 16.8 MB
  float* y      = (float*)p; p += (size_t)4096 * 1024 * 4;   // 16.8 MB
  u16*   yb     = (u16*)p;   p += (size_t)4096 * 1024 * 2;   // 8.4 MB
  u16*   hb     = (u16*)qkvb;            // 33.6 MB: spans qkvb + first half of ob
  u16*   vT     = (u16*)y;               // 8.4 MB: dead before ln2 writes y
  float* part1  = (float*)W1t;           // 16.8 MB: W1t + first half of x
  float* part2  = (float*)((char*)x + (size_t)4096 * 1024 * 2);  // rest of x + xb
  if (ws_size < (size_t)(p - (char*)d_ws)) return;

  prologue_k<<<dim3(4096 + 768), 256, 0, stream>>>(
      emb, ln1w, ln1b, x, xb, Wq, Wk, Wv, Wqkv_t);

  qkv_plus_k<<<dim3(768 + 2048), 256, 0, stream>>>(
      xb, Wqkv_t, bq, bk, bv, qkvb, W1, W2, W1t, W2t);

  vtrans_k<<<dim3(32, 32), 256, 0, stream>>>(qkvb + (size_t)64 * 2048 * 64, vT);

  attn_k<<<dim3(16, 32), 512, 0, stream>>>(qkvb, vT, ob);

  ln_k<<<dim3(4096), 256, 0, stream>>>(x, ob, ln2w, ln2b, y, yb);

  ffn1_gemm<<<dim3(32, 32), 256, 0, stream>>>(yb, W1t, b1, hb);

  ffn2_gemm<<<dim3(32, 8, 3), 256, 0, stream>>>(hb, W2t, b2, y, out, part1, part2);

  reduce2_k<<<dim3(4096), 256, 0, stream>>>(out, part1, part2);
}